// Round 1
// baseline (363.640 us; speedup 1.0000x reference)
//
#include <hip/hip_runtime.h>

// SNN: 2-layer LIF, T=4096 steps, B=1024, 6->10->27 neurons.
// One wave (64 threads) per batch element: lane i<10 owns mem1[i], lane j<27 owns mem2[j].
// Layer-1 currents are state-free -> precomputed t-parallel (lane=timestep) into LDS.
// Layer-2 matmul replaced by two 32-row LDS tables indexed by the 5-bit halves of the
// wave-uniform spike ballot mask. Reset flag == previous step's spike compare.

#define T_STEPS 4096
#define BETA 0.9f
#define THRESH 1.0f
#define CH 64            // timesteps per chunk (= lanes)
#define NCHUNK (T_STEPS / CH)

__global__ __launch_bounds__(64, 1) void snn_kernel(
    const float* __restrict__ x,   // [B][6][T]
    const float* __restrict__ W1,  // [10][6]
    const float* __restrict__ b1,  // [10]
    const float* __restrict__ W2,  // [27][10]
    const float* __restrict__ b2,  // [27]
    float* __restrict__ out)       // [B][27]
{
    __shared__ float tabLo[32 * 28];      // tabLo[m][j] = b2[j] + sum_{i<5} bit_i(m)*W2[j][i]
    __shared__ float tabHi[32 * 28];      // tabHi[m][j] = sum_{i<5} bit_i(m)*W2[j][5+i]
    __shared__ float curBuf[2][10 * 68];  // [dbuf][neuron][t (padded 64->68 for banks)]

    const int l = threadIdx.x;
    const int b = blockIdx.x;

    // ---- build layer-2 lookup tables (once) ----
    if (l < 32) {
        for (int j = 0; j < 27; ++j) {
            float slo = b2[j];
            float shi = 0.0f;
            #pragma unroll
            for (int i = 0; i < 5; ++i) {
                if (l & (1 << i)) {
                    slo += W2[j * 10 + i];
                    shi += W2[j * 10 + 5 + i];
                }
            }
            tabLo[l * 28 + j] = slo;
            tabHi[l * 28 + j] = shi;
        }
    }

    // ---- W1, b1 into registers (uniform -> scalar regs) ----
    float w1r[60], b1r[10];
    #pragma unroll
    for (int i = 0; i < 10; ++i) {
        b1r[i] = b1[i];
        #pragma unroll
        for (int c = 0; c < 6; ++c) w1r[i * 6 + c] = W1[i * 6 + c];
    }

    __syncthreads();

    const int ri = (l < 10) ? l : 9;    // lanes >=10 shadow neuron 9 (broadcast reads)
    const int rj = (l < 27) ? l : 26;   // lanes >=27 shadow neuron 26

    float mem1 = 0.0f, mem2 = 0.0f;
    float spkf = 0.0f;    // layer-1 spike of previous step == this step's reset flag
    float rstf2 = 0.0f;   // layer-2 reset flag

    const float* xb = x + (size_t)b * 6 * T_STEPS;

    // prologue: load chunk 0's x (lane = timestep)
    float xv[6], xn[6];
    #pragma unroll
    for (int c = 0; c < 6; ++c) xv[c] = xb[c * T_STEPS + l];

    for (int k = 0; k < NCHUNK; ++k) {
        const int buf = k & 1;

        // prefetch next chunk's x (latency hides under this chunk's 64 steps)
        if (k + 1 < NCHUNK) {
            #pragma unroll
            for (int c = 0; c < 6; ++c) xn[c] = xb[c * T_STEPS + (k + 1) * CH + l];
        }

        // t-parallel cur1: this lane computes all 10 neurons for timestep k*CH + l
        #pragma unroll
        for (int i = 0; i < 10; ++i) {
            float acc = xv[0] * w1r[i * 6 + 0];
            acc = fmaf(xv[1], w1r[i * 6 + 1], acc);
            acc = fmaf(xv[2], w1r[i * 6 + 2], acc);
            acc = fmaf(xv[3], w1r[i * 6 + 3], acc);
            acc = fmaf(xv[4], w1r[i * 6 + 4], acc);
            acc = fmaf(xv[5], w1r[i * 6 + 5], acc);
            curBuf[buf][i * 68 + l] = acc + b1r[i];
        }
        __syncthreads();

        // ---- sequential phase: 64 steps, grouped by 8 for latency overlap ----
        const float* cp = &curBuf[buf][ri * 68];
        #pragma unroll 1
        for (int t8 = 0; t8 < CH; t8 += 8) {
            float4 q0 = *(const float4*)(cp + t8);
            float4 q1 = *(const float4*)(cp + t8 + 4);
            float c1v[8] = {q0.x, q0.y, q0.z, q0.w, q1.x, q1.y, q1.z, q1.w};

            int mlo[8], mhi[8];
            // phase A: mem1 recurrence + ballot masks (runs ahead of LDS reads)
            #pragma unroll
            for (int s = 0; s < 8; ++s) {
                float t1 = fmaf(BETA, mem1, c1v[s]);   // beta*mem1 + cur1
                mem1 = t1 - spkf;                       // - rst (== prev spike)
                bool spk = mem1 > THRESH;
                unsigned long long bal = __ballot(spk);
                spkf = spk ? 1.0f : 0.0f;
                mlo[s] = (int)(bal & 31);
                mhi[s] = (int)((bal >> 5) & 31);
            }
            // phase B: issue all 16 table reads (latency overlaps across the group)
            float tlo[8], thi[8];
            #pragma unroll
            for (int s = 0; s < 8; ++s) {
                tlo[s] = tabLo[mlo[s] * 28 + rj];
                thi[s] = tabHi[mhi[s] * 28 + rj];
            }
            // phase C: mem2 recurrence
            #pragma unroll
            for (int s = 0; s < 8; ++s) {
                float cur2 = tlo[s] + thi[s];           // b2 folded into tabLo
                float t2 = fmaf(BETA, mem2, cur2);
                mem2 = t2 - rstf2;
                rstf2 = (mem2 > THRESH) ? 1.0f : 0.0f;
            }
        }

        #pragma unroll
        for (int c = 0; c < 6; ++c) xv[c] = xn[c];
    }

    if (l < 27) {
        out[b * 27 + l] = (mem2 > THRESH) ? 1.0f : 0.0f;
    }
}

extern "C" void kernel_launch(void* const* d_in, const int* in_sizes, int n_in,
                              void* d_out, int out_size, void* d_ws, size_t ws_size,
                              hipStream_t stream) {
    const float* x  = (const float*)d_in[0];
    const float* W1 = (const float*)d_in[1];
    const float* b1 = (const float*)d_in[2];
    const float* W2 = (const float*)d_in[3];
    const float* b2 = (const float*)d_in[4];
    float* out = (float*)d_out;

    const int B = in_sizes[0] / (6 * T_STEPS);  // 1024
    snn_kernel<<<dim3(B), dim3(64), 0, stream>>>(x, W1, b1, W2, b2, out);
}

// Round 2
// 310.080 us; speedup vs baseline: 1.1727x; 1.1727x over previous
//
#include <hip/hip_runtime.h>

// SNN: 2-layer LIF, T=4096, B=1024, 6->10->27.
// One wave per batch element (1024 waves = 1/SIMD; wall time = 4096 * per-step cycles).
// Round-2 restructure:
//  - no __syncthreads (single-wave block; DS ops are in-order) -> x-prefetch never drains
//  - ballot mask kept in SGPRs (SALU and/shift), pre-scaled row offsets
//  - reset applied as cndmask(t1, t1-1, prev_cmp) -- bit-identical to sub of {0,1}
//  - software pipeline: mem1-chain(group g+1) overlaps table-read latency(group g),
//    mem2-chain(g) consumes after; c1 float4 loads issued before table reads so their
//    lgkmcnt wait doesn't drain the table-read queue.

#define T_STEPS 4096
#define BETA 0.9f
#define THRESH 1.0f
#define CH 64
#define NCHUNK (T_STEPS / CH)
#define GRP 8
#define NGRP (CH / GRP)

__global__ __launch_bounds__(64, 1) void snn_kernel(
    const float* __restrict__ x,   // [B][6][T]
    const float* __restrict__ W1,  // [10][6]
    const float* __restrict__ b1,  // [10]
    const float* __restrict__ W2,  // [27][10]
    const float* __restrict__ b2,  // [27]
    float* __restrict__ out)       // [B][27]
{
    __shared__ float tabLo[32 * 32];   // [m][j]: b2[j] + sum_{i<5} bit_i(m)*W2[j][i]
    __shared__ float tabHi[32 * 32];   // [m][j]: sum_{i<5} bit_i(m)*W2[j][5+i]
    __shared__ float curBuf[10 * 68];  // [neuron][t], 68*4=272B row stride (16B aligned, 2-way banks = free)

    const int l = threadIdx.x;
    const int b = blockIdx.x;

    // ---- layer-2 lookup tables (once; same construction/order as round 1 -> identical values) ----
    if (l < 32) {
        for (int j = 0; j < 27; ++j) {
            float slo = b2[j];
            float shi = 0.0f;
            #pragma unroll
            for (int i = 0; i < 5; ++i) {
                if (l & (1 << i)) {
                    slo += W2[j * 10 + i];
                    shi += W2[j * 10 + 5 + i];
                }
            }
            tabLo[l * 32 + j] = slo;
            tabHi[l * 32 + j] = shi;
        }
    }

    float w1r[60], b1r[10];
    #pragma unroll
    for (int i = 0; i < 10; ++i) {
        b1r[i] = b1[i];
        #pragma unroll
        for (int c = 0; c < 6; ++c) w1r[i * 6 + c] = W1[i * 6 + c];
    }

    const int ri = (l < 10) ? l : 9;    // lanes >=10 shadow neuron 9
    const int rj = (l < 27) ? l : 26;   // lanes >=27 shadow neuron 26

    float mem1 = 0.0f, mem2 = 0.0f;
    bool sp1 = false;   // layer-1 spike predicate of previous step (== reset flag)
    bool sp2 = false;   // layer-2

    const float* xb = x + (size_t)b * 6 * T_STEPS;
    float xv[6], xn[6];
    #pragma unroll
    for (int c = 0; c < 6; ++c) xv[c] = xb[c * T_STEPS + l];

    const float* cp = &curBuf[ri * 68];

    #pragma unroll 1
    for (int k = 0; k < NCHUNK; ++k) {
        // ---- t-parallel cur1 (lane = timestep); same fma order as round 1 ----
        #pragma unroll
        for (int i = 0; i < 10; ++i) {
            float acc = xv[0] * w1r[i * 6 + 0];
            acc = fmaf(xv[1], w1r[i * 6 + 1], acc);
            acc = fmaf(xv[2], w1r[i * 6 + 2], acc);
            acc = fmaf(xv[3], w1r[i * 6 + 3], acc);
            acc = fmaf(xv[4], w1r[i * 6 + 4], acc);
            acc = fmaf(xv[5], w1r[i * 6 + 5], acc);
            curBuf[i * 68 + l] = acc + b1r[i];
        }

        // prefetch next chunk's x -- no barrier anywhere, so this latency floats freely
        if (k + 1 < NCHUNK) {
            #pragma unroll
            for (int c = 0; c < 6; ++c) xn[c] = xb[c * T_STEPS + (k + 1) * CH + l];
        }

        // ---- sequential phase: 64 steps, 8-step groups, software-pipelined ----
        unsigned mlo[GRP], mhi[GRP];   // wave-uniform (SGPR) pre-scaled row offsets

        {   // prologue: A(0)
            float4 q0 = *(const float4*)(cp + 0);
            float4 q1 = *(const float4*)(cp + 4);
            float c1v[8] = {q0.x, q0.y, q0.z, q0.w, q1.x, q1.y, q1.z, q1.w};
            #pragma unroll
            for (int s = 0; s < 8; ++s) {
                float t1 = fmaf(BETA, mem1, c1v[s]);
                mem1 = sp1 ? (t1 - THRESH) : t1;      // == t1 - rst*THRESH, bit-identical
                sp1 = mem1 > THRESH;
                unsigned m = (unsigned)__ballot(sp1); // same v_cmp as sp1 -> SGPR pair
                mlo[s] = (m & 31u) << 5;              // row offset in floats (x32)
                mhi[s] = ((m >> 5) & 31u) << 5;
            }
        }

        #pragma unroll
        for (int g = 0; g < NGRP; ++g) {
            const bool more = (g + 1 < NGRP);         // compile-time (g fully unrolled)

            // (1) issue next group's c1 loads FIRST (so A(g+1)'s wait leaves table reads in flight)
            float c1n[8];
            if (more) {
                float4 p0 = *(const float4*)(cp + (g + 1) * 8);
                float4 p1 = *(const float4*)(cp + (g + 1) * 8 + 4);
                c1n[0] = p0.x; c1n[1] = p0.y; c1n[2] = p0.z; c1n[3] = p0.w;
                c1n[4] = p1.x; c1n[5] = p1.y; c1n[6] = p1.z; c1n[7] = p1.w;
            }

            // (2) issue this group's 16 table reads (uniform row -> broadcast, conflict-free)
            float tlo[8], thi[8];
            #pragma unroll
            for (int s = 0; s < 8; ++s) {
                tlo[s] = tabLo[mlo[s] + rj];
                thi[s] = tabHi[mhi[s] + rj];
            }

            // (3) mem1 chain for group g+1 -- overlaps table-read latency
            unsigned nlo[GRP], nhi[GRP];
            if (more) {
                #pragma unroll
                for (int s = 0; s < 8; ++s) {
                    float t1 = fmaf(BETA, mem1, c1n[s]);
                    mem1 = sp1 ? (t1 - THRESH) : t1;
                    sp1 = mem1 > THRESH;
                    unsigned m = (unsigned)__ballot(sp1);
                    nlo[s] = (m & 31u) << 5;
                    nhi[s] = ((m >> 5) & 31u) << 5;
                }
            }

            // (4) mem2 chain for group g
            #pragma unroll
            for (int s = 0; s < 8; ++s) {
                float cur2 = tlo[s] + thi[s];          // b2 folded into tabLo
                float t2 = fmaf(BETA, mem2, cur2);
                mem2 = sp2 ? (t2 - THRESH) : t2;
                sp2 = mem2 > THRESH;
            }

            if (more) {
                #pragma unroll
                for (int s = 0; s < 8; ++s) { mlo[s] = nlo[s]; mhi[s] = nhi[s]; }
            }
        }

        if (k + 1 < NCHUNK) {
            #pragma unroll
            for (int c = 0; c < 6; ++c) xv[c] = xn[c];
        }
    }

    if (l < 27) {
        out[b * 27 + l] = sp2 ? 1.0f : 0.0f;
    }
}

extern "C" void kernel_launch(void* const* d_in, const int* in_sizes, int n_in,
                              void* d_out, int out_size, void* d_ws, size_t ws_size,
                              hipStream_t stream) {
    const float* x  = (const float*)d_in[0];
    const float* W1 = (const float*)d_in[1];
    const float* b1 = (const float*)d_in[2];
    const float* W2 = (const float*)d_in[3];
    const float* b2 = (const float*)d_in[4];
    float* out = (float*)d_out;

    const int B = in_sizes[0] / (6 * T_STEPS);  // 1024
    snn_kernel<<<dim3(B), dim3(64), 0, stream>>>(x, W1, b1, W2, b2, out);
}